// Round 6
// baseline (204.573 us; speedup 1.0000x reference)
//
#include <hip/hip_runtime.h>

// PlatonicConv: G=12, H_EFF=2, HEAD_D=16, GH=24, N=2048 (32 graphs x 64 nodes),
// IN_C=EMB=OUT_C=384. Fully-connected edges per graph => dense attention S=64,D=16
// per (graph, group-head). f32 in/out; bf16 MFMA inside.
//
// R6: ONE normal launch, 768 blocks x 256 thr, manual deadlock-safe grid barrier.
//   Co-residency guaranteed: __launch_bounds__(256,4) => VGPR<=128 => 4 blk/CU by
//   regs; LDS 37632B*4 = 150KB <= 160KB/CU; waves 16 <= 32  => capacity 1024 >= 768.
//   pre:    scatter-transpose Wo -> WoT bf16 (blocks 0..575 cover it exactly)
//   phaseA: stage own W-slice f32->bf16 LDS (RTNE), QKV GEMM (A = f32 x direct,
//           perm-packed; B = LDS), bias+RoPE, dense attention -> attn bf16
//   [grid barrier: syncthreads-drain + threadfence + atomic + agent-scope poll]
//   phaseB: out-proj rows gr*64..+64, cols gh*16..+16 from attn/WoT (L2-hot)

#define NNODES   2048
#define KDIM     384
#define NGRAPHS  32
#define GHEADS   24
#define NBLOCKS  (NGRAPHS * GHEADS)      // 768
#define WSROW    392      // padded LDS row (shorts): 196 words, 196%32=4

typedef __attribute__((ext_vector_type(8))) short    short8;
typedef __attribute__((ext_vector_type(4))) float    f32x4;
typedef __attribute__((ext_vector_type(4))) unsigned u32x4;

__device__ __forceinline__ short f2bf(float f) {      // RTNE (cold paths)
    unsigned u = __builtin_bit_cast(unsigned, f);
    u += 0x7FFFu + ((u >> 16) & 1u);
    return (short)(u >> 16);
}
// pack bf16(lo), bf16(hi) (truncating) into one u32 via v_perm_b32 (hot path)
__device__ __forceinline__ unsigned pk2bf(float lo, float hi) {
    return __builtin_amdgcn_perm(__builtin_bit_cast(unsigned, hi),
                                 __builtin_bit_cast(unsigned, lo), 0x07060302u);
}

__global__ __launch_bounds__(256, 4) void mega_kernel(
    const float* __restrict__ x,      // [2048][384]
    const float* __restrict__ pos,    // [2048][3]
    const float* __restrict__ Wq, const float* __restrict__ bq,
    const float* __restrict__ Wk, const float* __restrict__ bk,
    const float* __restrict__ Wv, const float* __restrict__ bv,
    const float* __restrict__ Wo, const float* __restrict__ bo,
    const float* __restrict__ freqs,  // [3][2][8]
    short* __restrict__ WoT,          // [384][384] bf16 scratch
    short* __restrict__ attn_out,     // [2048][384] bf16 scratch
    unsigned* __restrict__ bar,       // pre-zeroed barrier counter
    float* __restrict__ out)          // [2048][384] f32
{
    __shared__ __align__(16) char smem[3 * 16 * WSROW * 2];   // 37632 B
    const int tid = threadIdx.x;
    const int gr  = blockIdx.x / GHEADS;
    const int gh  = blockIdx.x - gr * GHEADS;

    // ---- pre: Wo scatter transpose (576*256 = 147456 = 384*384 exactly) ----
    {
        const int u = blockIdx.x * 256 + tid;
        if (u < KDIM * KDIM)
            WoT[u] = f2bf(Wo[(size_t)(u % KDIM) * KDIM + u / KDIM]);
    }

    // ---- phase 0: stage this gh's weight slice into LDS (bf16, RTNE) ------
    // WS[mat][c][k] rows padded to WSROW shorts; k-pair packed b32 writes.
    short* WS = reinterpret_cast<short*>(smem);
    for (int task = tid; task < 576; task += 256) {
        const int mat = task / 192;           // 0=q 1=k 2=v
        const int kp  = task - mat * 192;
        const int k   = kp * 2;
        const float* W = (mat == 0) ? Wq : (mat == 1) ? Wk : Wv;
        const float* s0 = W + (size_t)k * KDIM + gh * 16;
        const float* s1 = s0 + KDIM;
        f32x4 r0[4], r1[4];
        #pragma unroll
        for (int i = 0; i < 4; ++i) {
            r0[i] = reinterpret_cast<const f32x4*>(s0)[i];
            r1[i] = reinterpret_cast<const f32x4*>(s1)[i];
        }
        unsigned* dst = reinterpret_cast<unsigned*>(WS + (size_t)mat * 16 * WSROW + k);
        #pragma unroll
        for (int c = 0; c < 16; ++c) {
            const unsigned lo = (unsigned)(unsigned short)f2bf(r0[c >> 2][c & 3]);
            const unsigned hi = (unsigned)(unsigned short)f2bf(r1[c >> 2][c & 3]);
            dst[c * (WSROW / 2)] = lo | (hi << 16);
        }
    }
    __syncthreads();

    // ---- phase 1: QKV GEMM (16 rows/wave x 16 cols, K=384) ----------------
    const int w    = tid >> 6;
    const int lane = tid & 63;
    const int fr   = lane & 15;
    const int hi   = lane >> 4;

    const float* aRow = x + (size_t)(gr * 64 + w * 16 + fr) * KDIM + hi * 8;
    const short* wsq = WS + (size_t)fr * WSROW + hi * 8;
    const short* wsk = wsq + (size_t)16 * WSROW;
    const short* wsv = wsk + (size_t)16 * WSROW;

    f32x4 acc[3];
    acc[0] = (f32x4){0.f, 0.f, 0.f, 0.f};
    acc[1] = acc[0];
    acc[2] = acc[0];

    #pragma unroll 4
    for (int kt = 0; kt < KDIM; kt += 32) {
        f32x4 a0 = *reinterpret_cast<const f32x4*>(aRow + kt);
        f32x4 a1 = *reinterpret_cast<const f32x4*>(aRow + kt + 4);
        u32x4 ap;
        ap[0] = pk2bf(a0[0], a0[1]);
        ap[1] = pk2bf(a0[2], a0[3]);
        ap[2] = pk2bf(a1[0], a1[1]);
        ap[3] = pk2bf(a1[2], a1[3]);
        short8 af = __builtin_bit_cast(short8, ap);
        short8 b0 = *reinterpret_cast<const short8*>(wsq + kt);
        short8 b1 = *reinterpret_cast<const short8*>(wsk + kt);
        short8 b2 = *reinterpret_cast<const short8*>(wsv + kt);
        acc[0] = __builtin_amdgcn_mfma_f32_16x16x32_bf16(af, b0, acc[0], 0, 0, 0);
        acc[1] = __builtin_amdgcn_mfma_f32_16x16x32_bf16(af, b1, acc[1], 0, 0, 0);
        acc[2] = __builtin_amdgcn_mfma_f32_16x16x32_bf16(af, b2, acc[2], 0, 0, 0);
    }
    __syncthreads();   // all waves done reading WS; LDS re-purposed below

    // ---- phase 2: bias + RoPE, publish q/k/v to LDS -----------------------
    float (*q_lds)[20] = reinterpret_cast<float(*)[20]>(smem);
    float (*k_lds)[20] = reinterpret_cast<float(*)[20]>(smem + 5120);
    float (*v_lds)[20] = reinterpret_cast<float(*)[20]>(smem + 10240);

    const float bias_q = bq[gh * 16 + fr];
    const float bias_k = bk[gh * 16 + fr];
    const float bias_v = bv[gh * 16 + fr];
    const int   h = gh & 1;
    const int   f = fr >> 1;
    const float F0 = freqs[h * 8 + f];
    const float F1 = freqs[16 + h * 8 + f];
    const float F2 = freqs[32 + h * 8 + f];

    #pragma unroll
    for (int rr = 0; rr < 4; ++rr) {
        const int row  = w * 16 + hi * 4 + rr;       // local node row 0..63
        const int grow = gr * 64 + row;
        float qv = acc[0][rr] + bias_q;
        float kv = acc[1][rr] + bias_k;
        float vv = acc[2][rr] + bias_v;
        const float th = pos[grow * 3] * F0 + pos[grow * 3 + 1] * F1
                       + pos[grow * 3 + 2] * F2;
        const float cs = __cosf(th);
        const float sn = __sinf(th);
        const float qo = __shfl_xor(qv, 1, 64);
        const float ko = __shfl_xor(kv, 1, 64);
        qv = (fr & 1) ? (qo * sn + qv * cs) : (qv * cs - qo * sn);
        kv = (fr & 1) ? (ko * sn + kv * cs) : (kv * cs - ko * sn);
        q_lds[row][fr] = qv;
        k_lds[row][fr] = kv;
        v_lds[row][fr] = vv;
    }
    __syncthreads();

    // ---- phase 3: attention, lane = (qrow fr, k-quarter hi) ---------------
    const int qrow = w * 16 + fr;
    f32x4 q0 = *reinterpret_cast<const f32x4*>(&q_lds[qrow][0]);
    f32x4 q1 = *reinterpret_cast<const f32x4*>(&q_lds[qrow][4]);
    f32x4 q2 = *reinterpret_cast<const f32x4*>(&q_lds[qrow][8]);
    f32x4 q3 = *reinterpret_cast<const f32x4*>(&q_lds[qrow][12]);

    float sc[16];
    #pragma unroll
    for (int j = 0; j < 16; ++j) {
        const float* kp = &k_lds[hi * 16 + j][0];
        f32x4 k0 = reinterpret_cast<const f32x4*>(kp)[0];
        f32x4 k1 = reinterpret_cast<const f32x4*>(kp)[1];
        f32x4 k2 = reinterpret_cast<const f32x4*>(kp)[2];
        f32x4 k3 = reinterpret_cast<const f32x4*>(kp)[3];
        float a = q0[0]*k0[0] + q0[1]*k0[1] + q0[2]*k0[2] + q0[3]*k0[3]
                + q1[0]*k1[0] + q1[1]*k1[1] + q1[2]*k1[2] + q1[3]*k1[3]
                + q2[0]*k2[0] + q2[1]*k2[1] + q2[2]*k2[2] + q2[3]*k2[3]
                + q3[0]*k3[0] + q3[1]*k3[1] + q3[2]*k3[2] + q3[3]*k3[3];
        sc[j] = a * 0.25f;
    }

    float mx = sc[0];
    #pragma unroll
    for (int j = 1; j < 16; ++j) mx = fmaxf(mx, sc[j]);
    mx = fmaxf(mx, __shfl_xor(mx, 16, 64));
    mx = fmaxf(mx, __shfl_xor(mx, 32, 64));

    float den = 0.f;
    #pragma unroll
    for (int j = 0; j < 16; ++j) {
        sc[j] = __expf(sc[j] - mx);
        den += sc[j];
    }
    den += __shfl_xor(den, 16, 64);
    den += __shfl_xor(den, 32, 64);

    float o[16];
    #pragma unroll
    for (int d = 0; d < 16; ++d) o[d] = 0.f;
    #pragma unroll
    for (int j = 0; j < 16; ++j) {
        const float p = sc[j];
        const float* vp = &v_lds[hi * 16 + j][0];
        f32x4 v0 = reinterpret_cast<const f32x4*>(vp)[0];
        f32x4 v1 = reinterpret_cast<const f32x4*>(vp)[1];
        f32x4 v2 = reinterpret_cast<const f32x4*>(vp)[2];
        f32x4 v3 = reinterpret_cast<const f32x4*>(vp)[3];
        #pragma unroll
        for (int d = 0; d < 4; ++d) {
            o[d]      += p * v0[d];
            o[4 + d]  += p * v1[d];
            o[8 + d]  += p * v2[d];
            o[12 + d] += p * v3[d];
        }
    }
    #pragma unroll
    for (int d = 0; d < 16; ++d) {
        o[d] += __shfl_xor(o[d], 16, 64);
        o[d] += __shfl_xor(o[d], 32, 64);
    }

    if (hi == 0) {
        const float inv = 1.0f / den;
        short8 r0, r1;
        #pragma unroll
        for (int d = 0; d < 8; ++d) {
            r0[d] = f2bf(o[d] * inv);
            r1[d] = f2bf(o[8 + d] * inv);
        }
        short* op = attn_out + (size_t)(gr * 64 + qrow) * KDIM + gh * 16;
        *reinterpret_cast<short8*>(op)     = r0;
        *reinterpret_cast<short8*>(op + 8) = r1;
    }

    // ---- manual grid barrier (all 768 blocks co-resident by construction) --
    __syncthreads();                 // per-wave vmcnt drain: stores are in L2
    if (tid == 0) {
        __threadfence();             // device-scope release (L2 writeback)
        atomicAdd(bar, 1u);
        while (__hip_atomic_load(bar, __ATOMIC_RELAXED,
                                 __HIP_MEMORY_SCOPE_AGENT) < (unsigned)NBLOCKS)
            __builtin_amdgcn_s_sleep(8);
        __threadfence();             // acquire (invalidate stale caches)
    }
    __syncthreads();

    // ---- phase B: out-proj rows gr*64..+64, cols gh*16..+16 ---------------
    {
        const short* aP = attn_out + (size_t)(gr * 64 + w * 16 + fr) * KDIM + hi * 8;
        const short* bP = WoT + (size_t)(gh * 16 + fr) * KDIM + hi * 8;

        f32x4 acc4 = (f32x4){0.f, 0.f, 0.f, 0.f};
        #pragma unroll
        for (int kt = 0; kt < KDIM; kt += 32) {
            short8 af = *reinterpret_cast<const short8*>(aP + kt);
            short8 bf = *reinterpret_cast<const short8*>(bP + kt);
            acc4 = __builtin_amdgcn_mfma_f32_16x16x32_bf16(af, bf, acc4, 0, 0, 0);
        }

        const int c    = gh * 16 + fr;
        const float bv = bo[c];
        const int rowb = gr * 64 + w * 16 + hi * 4;
        #pragma unroll
        for (int rr = 0; rr < 4; ++rr)
            out[(size_t)(rowb + rr) * KDIM + c] = acc4[rr] + bv;
    }
}

extern "C" void kernel_launch(void* const* d_in, const int* in_sizes, int n_in,
                              void* d_out, int out_size, void* d_ws, size_t ws_size,
                              hipStream_t stream) {
    const float* x    = (const float*)d_in[0];
    const float* pos  = (const float*)d_in[1];
    const float* Wq   = (const float*)d_in[2];
    const float* bq   = (const float*)d_in[3];
    const float* Wk   = (const float*)d_in[4];
    const float* bk   = (const float*)d_in[5];
    const float* Wv   = (const float*)d_in[6];
    const float* bv   = (const float*)d_in[7];
    const float* Wo   = (const float*)d_in[8];
    const float* bo   = (const float*)d_in[9];
    const float* rope = (const float*)d_in[10];
    // d_in[11]=src, d_in[12]=dst: fixed fully-connected pattern, unused.

    char* ws = (char*)d_ws;
    short*    WoT  = (short*)(ws);             // 384*384 bf16 = 294,912 B
    short*    attn = (short*)(ws + 294912);    // 2048*384 bf16 = 1,572,864 B
    unsigned* bar  = (unsigned*)(ws + 1867776);

    hipMemsetAsync(bar, 0, sizeof(unsigned), stream);

    mega_kernel<<<NBLOCKS, 256, 0, stream>>>(
        x, pos, Wq, bq, Wk, bk, Wv, bv, Wo, bo, rope,
        WoT, attn, bar, (float*)d_out);
}

// Round 7
// 107.404 us; speedup vs baseline: 1.9047x; 1.9047x over previous
//
#include <hip/hip_runtime.h>

// PlatonicConv: G=12, H_EFF=2, HEAD_D=16, GH=24, N=2048 (32 graphs x 64 nodes),
// IN_C=EMB=OUT_C=384. Fully-connected edges per graph => dense attention S=64,D=16
// per (graph, group-head). f32 in/out; bf16 MFMA inside.
//
// R7 = R4 structure (2 kernels; kernel boundary provides cross-XCD coherence
// at 1 wbl2+inv per XCD, vs R6's per-block fence storm which cost 130us):
//   KA fused: blocks 0..143 transpose Wo -> WoT bf16 (coalesced via LDS tile);
//             blocks 144..911: per (graph, gh): stage own W-slice f32->bf16 LDS
//             (RTNE, packed b32 writes), QKV GEMM (A = f32 x direct + RTNE pack,
//             B = LDS; kt=0 A-loads issued before staging), bias+RoPE, attention.
//   KB out-proj: 768 one-wave blocks, 16x64 tiles, direct-global frags.

#define NNODES   2048
#define KDIM     384
#define NGRAPHS  32
#define GHEADS   24
#define WSROW    392      // padded LDS row (shorts): 784B, 16B-aligned

typedef __attribute__((ext_vector_type(8))) short short8;
typedef __attribute__((ext_vector_type(4))) float f32x4;

__device__ __forceinline__ short f2bf(float f) {      // RTNE
    unsigned u = __builtin_bit_cast(unsigned, f);
    u += 0x7FFFu + ((u >> 16) & 1u);
    return (short)(u >> 16);
}
__device__ __forceinline__ unsigned pk2bf_rtne(float lo, float hi) {
    const unsigned l = (unsigned)(unsigned short)f2bf(lo);
    const unsigned h = (unsigned)(unsigned short)f2bf(hi);
    return l | (h << 16);
}

// ---- KA: fused {Wo transpose} | {W-slice prep + QKV GEMM + RoPE + attn} ----
__global__ __launch_bounds__(256) void fused_kernel(
    const float* __restrict__ x,      // [2048][384]
    const float* __restrict__ pos,    // [2048][3]
    const float* __restrict__ Wq, const float* __restrict__ bq,
    const float* __restrict__ Wk, const float* __restrict__ bk,
    const float* __restrict__ Wv, const float* __restrict__ bv,
    const float* __restrict__ Wo,
    const float* __restrict__ freqs,  // [3][2][8]
    short* __restrict__ WoT,          // [384][384] bf16 out
    short* __restrict__ attn_out)     // [2048][384] bf16 out
{
    __shared__ __align__(16) char smem[3 * 16 * WSROW * 2];   // 37632 B
    const int tid = threadIdx.x;

    if (blockIdx.x < 144) {
        // transpose one 32x32 tile of Wo: WoT[n][k] = Wo[k][n], f32->bf16
        float (*tile)[33] = reinterpret_cast<float(*)[33]>(smem);
        const int t  = blockIdx.x;
        const int k0 = (t / 12) * 32;
        const int n0 = (t % 12) * 32;
        const int cx = tid & 31;
        const int ty = tid >> 5;
        #pragma unroll
        for (int i = 0; i < 4; ++i) {
            const int rr = ty + 8 * i;
            tile[rr][cx] = Wo[(size_t)(k0 + rr) * KDIM + n0 + cx];
        }
        __syncthreads();
        #pragma unroll
        for (int i = 0; i < 4; ++i) {
            const int rr = ty + 8 * i;
            WoT[(size_t)(n0 + rr) * KDIM + k0 + cx] = f2bf(tile[cx][rr]);
        }
        return;
    }

    const int blk = blockIdx.x - 144;
    const int gr  = blk / GHEADS;
    const int gh  = blk - gr * GHEADS;

    const int w    = tid >> 6;
    const int lane = tid & 63;
    const int fr   = lane & 15;
    const int hi   = lane >> 4;

    // issue-early: kt=0 A-loads (hide global latency under weight staging)
    const float* aRow = x + (size_t)(gr * 64 + w * 16 + fr) * KDIM + hi * 8;
    f32x4 a0p = *reinterpret_cast<const f32x4*>(aRow);
    f32x4 a1p = *reinterpret_cast<const f32x4*>(aRow + 4);

    // ---- phase 0: stage this gh's weight slice into LDS (bf16 RTNE) -------
    // WS[mat][c][k] rows padded to WSROW shorts; k-pair packed b32 writes.
    short* WS = reinterpret_cast<short*>(smem);
    for (int task = tid; task < 576; task += 256) {
        const int mat = task / 192;           // 0=q 1=k 2=v
        const int kp  = task - mat * 192;
        const int k   = kp * 2;
        const float* W = (mat == 0) ? Wq : (mat == 1) ? Wk : Wv;
        const float* s0 = W + (size_t)k * KDIM + gh * 16;
        const float* s1 = s0 + KDIM;
        f32x4 r0[4], r1[4];
        #pragma unroll
        for (int i = 0; i < 4; ++i) {
            r0[i] = reinterpret_cast<const f32x4*>(s0)[i];
            r1[i] = reinterpret_cast<const f32x4*>(s1)[i];
        }
        unsigned* dst = reinterpret_cast<unsigned*>(WS + (size_t)mat * 16 * WSROW + k);
        #pragma unroll
        for (int c = 0; c < 16; ++c)
            dst[c * (WSROW / 2)] = pk2bf_rtne(r0[c >> 2][c & 3], r1[c >> 2][c & 3]);
    }
    __syncthreads();

    // ---- phase 1: QKV GEMM (16 rows/wave x 16 cols, K=384) ----------------
    const short* wsq = WS + (size_t)fr * WSROW + hi * 8;
    const short* wsk = wsq + (size_t)16 * WSROW;
    const short* wsv = wsk + (size_t)16 * WSROW;

    f32x4 acc[3];
    acc[0] = (f32x4){0.f, 0.f, 0.f, 0.f};
    acc[1] = acc[0];
    acc[2] = acc[0];

    #pragma unroll 4
    for (int kt = 0; kt < KDIM; kt += 32) {
        f32x4 a0, a1;
        if (kt == 0) { a0 = a0p; a1 = a1p; }
        else {
            a0 = *reinterpret_cast<const f32x4*>(aRow + kt);
            a1 = *reinterpret_cast<const f32x4*>(aRow + kt + 4);
        }
        short8 af;
        af[0] = f2bf(a0[0]); af[1] = f2bf(a0[1]); af[2] = f2bf(a0[2]); af[3] = f2bf(a0[3]);
        af[4] = f2bf(a1[0]); af[5] = f2bf(a1[1]); af[6] = f2bf(a1[2]); af[7] = f2bf(a1[3]);
        short8 b0 = *reinterpret_cast<const short8*>(wsq + kt);
        short8 b1 = *reinterpret_cast<const short8*>(wsk + kt);
        short8 b2 = *reinterpret_cast<const short8*>(wsv + kt);
        acc[0] = __builtin_amdgcn_mfma_f32_16x16x32_bf16(af, b0, acc[0], 0, 0, 0);
        acc[1] = __builtin_amdgcn_mfma_f32_16x16x32_bf16(af, b1, acc[1], 0, 0, 0);
        acc[2] = __builtin_amdgcn_mfma_f32_16x16x32_bf16(af, b2, acc[2], 0, 0, 0);
    }
    __syncthreads();   // all waves done reading WS; LDS re-purposed below

    // ---- phase 2: bias + RoPE, publish q/k/v to LDS -----------------------
    float (*q_lds)[20] = reinterpret_cast<float(*)[20]>(smem);
    float (*k_lds)[20] = reinterpret_cast<float(*)[20]>(smem + 5120);
    float (*v_lds)[20] = reinterpret_cast<float(*)[20]>(smem + 10240);

    const float bias_q = bq[gh * 16 + fr];
    const float bias_k = bk[gh * 16 + fr];
    const float bias_v = bv[gh * 16 + fr];
    const int   h = gh & 1;
    const int   f = fr >> 1;
    const float F0 = freqs[h * 8 + f];
    const float F1 = freqs[16 + h * 8 + f];
    const float F2 = freqs[32 + h * 8 + f];

    #pragma unroll
    for (int rr = 0; rr < 4; ++rr) {
        const int row  = w * 16 + hi * 4 + rr;       // local node row 0..63
        const int grow = gr * 64 + row;
        float qv = acc[0][rr] + bias_q;
        float kv = acc[1][rr] + bias_k;
        float vv = acc[2][rr] + bias_v;
        const float th = pos[grow * 3] * F0 + pos[grow * 3 + 1] * F1
                       + pos[grow * 3 + 2] * F2;
        const float cs = __cosf(th);
        const float sn = __sinf(th);
        const float qo = __shfl_xor(qv, 1, 64);
        const float ko = __shfl_xor(kv, 1, 64);
        qv = (fr & 1) ? (qo * sn + qv * cs) : (qv * cs - qo * sn);
        kv = (fr & 1) ? (ko * sn + kv * cs) : (kv * cs - ko * sn);
        q_lds[row][fr] = qv;
        k_lds[row][fr] = kv;
        v_lds[row][fr] = vv;
    }
    __syncthreads();

    // ---- phase 3: attention, lane = (qrow fr, k-quarter hi) ---------------
    const int qrow = w * 16 + fr;
    f32x4 q0 = *reinterpret_cast<const f32x4*>(&q_lds[qrow][0]);
    f32x4 q1 = *reinterpret_cast<const f32x4*>(&q_lds[qrow][4]);
    f32x4 q2 = *reinterpret_cast<const f32x4*>(&q_lds[qrow][8]);
    f32x4 q3 = *reinterpret_cast<const f32x4*>(&q_lds[qrow][12]);

    float sc[16];
    #pragma unroll
    for (int j = 0; j < 16; ++j) {
        const float* kp = &k_lds[hi * 16 + j][0];
        f32x4 k0 = reinterpret_cast<const f32x4*>(kp)[0];
        f32x4 k1 = reinterpret_cast<const f32x4*>(kp)[1];
        f32x4 k2 = reinterpret_cast<const f32x4*>(kp)[2];
        f32x4 k3 = reinterpret_cast<const f32x4*>(kp)[3];
        float a = q0[0]*k0[0] + q0[1]*k0[1] + q0[2]*k0[2] + q0[3]*k0[3]
                + q1[0]*k1[0] + q1[1]*k1[1] + q1[2]*k1[2] + q1[3]*k1[3]
                + q2[0]*k2[0] + q2[1]*k2[1] + q2[2]*k2[2] + q2[3]*k2[3]
                + q3[0]*k3[0] + q3[1]*k3[1] + q3[2]*k3[2] + q3[3]*k3[3];
        sc[j] = a * 0.25f;
    }

    float mx = sc[0];
    #pragma unroll
    for (int j = 1; j < 16; ++j) mx = fmaxf(mx, sc[j]);
    mx = fmaxf(mx, __shfl_xor(mx, 16, 64));
    mx = fmaxf(mx, __shfl_xor(mx, 32, 64));

    float den = 0.f;
    #pragma unroll
    for (int j = 0; j < 16; ++j) {
        sc[j] = __expf(sc[j] - mx);
        den += sc[j];
    }
    den += __shfl_xor(den, 16, 64);
    den += __shfl_xor(den, 32, 64);

    float o[16];
    #pragma unroll
    for (int d = 0; d < 16; ++d) o[d] = 0.f;
    #pragma unroll
    for (int j = 0; j < 16; ++j) {
        const float p = sc[j];
        const float* vp = &v_lds[hi * 16 + j][0];
        f32x4 v0 = reinterpret_cast<const f32x4*>(vp)[0];
        f32x4 v1 = reinterpret_cast<const f32x4*>(vp)[1];
        f32x4 v2 = reinterpret_cast<const f32x4*>(vp)[2];
        f32x4 v3 = reinterpret_cast<const f32x4*>(vp)[3];
        #pragma unroll
        for (int d = 0; d < 4; ++d) {
            o[d]      += p * v0[d];
            o[4 + d]  += p * v1[d];
            o[8 + d]  += p * v2[d];
            o[12 + d] += p * v3[d];
        }
    }
    #pragma unroll
    for (int d = 0; d < 16; ++d) {
        o[d] += __shfl_xor(o[d], 16, 64);
        o[d] += __shfl_xor(o[d], 32, 64);
    }

    if (hi == 0) {
        const float inv = 1.0f / den;
        short8 r0, r1;
        #pragma unroll
        for (int d = 0; d < 8; ++d) {
            r0[d] = f2bf(o[d] * inv);
            r1[d] = f2bf(o[8 + d] * inv);
        }
        short* op = attn_out + (size_t)(gr * 64 + qrow) * KDIM + gh * 16;
        *reinterpret_cast<short8*>(op)     = r0;
        *reinterpret_cast<short8*>(op + 8) = r1;
    }
}

// ---- KB: out-projection, 1-wave blocks, 16x64 tile, no LDS/barriers -------
__global__ __launch_bounds__(64) void out_gemm_kernel(
    const short* __restrict__ A,     // attn bf16 [2048][384]
    const short* __restrict__ BT,    // WoT [384][384] bf16 (out cols as rows)
    const float* __restrict__ bias,
    float* __restrict__ C)           // [2048][384] f32
{
    const int r0   = blockIdx.x * 16;
    const int c0   = blockIdx.y * 64;
    const int lane = threadIdx.x;
    const int fr   = lane & 15;
    const int hi   = lane >> 4;

    const short* aP  = A + (size_t)(r0 + fr) * KDIM + hi * 8;
    const short* b0P = BT + (size_t)(c0 + fr) * KDIM + hi * 8;
    const short* b1P = b0P + (size_t)16 * KDIM;
    const short* b2P = b1P + (size_t)16 * KDIM;
    const short* b3P = b2P + (size_t)16 * KDIM;

    f32x4 acc[4];
    acc[0] = (f32x4){0.f, 0.f, 0.f, 0.f};
    acc[1] = acc[0]; acc[2] = acc[0]; acc[3] = acc[0];

    #pragma unroll 4
    for (int kt = 0; kt < KDIM; kt += 32) {
        short8 af = *reinterpret_cast<const short8*>(aP + kt);
        short8 f0 = *reinterpret_cast<const short8*>(b0P + kt);
        short8 f1 = *reinterpret_cast<const short8*>(b1P + kt);
        short8 f2 = *reinterpret_cast<const short8*>(b2P + kt);
        short8 f3 = *reinterpret_cast<const short8*>(b3P + kt);
        acc[0] = __builtin_amdgcn_mfma_f32_16x16x32_bf16(af, f0, acc[0], 0, 0, 0);
        acc[1] = __builtin_amdgcn_mfma_f32_16x16x32_bf16(af, f1, acc[1], 0, 0, 0);
        acc[2] = __builtin_amdgcn_mfma_f32_16x16x32_bf16(af, f2, acc[2], 0, 0, 0);
        acc[3] = __builtin_amdgcn_mfma_f32_16x16x32_bf16(af, f3, acc[3], 0, 0, 0);
    }

    #pragma unroll
    for (int ct = 0; ct < 4; ++ct) {
        const int c    = c0 + ct * 16 + fr;
        const float bv = bias[c];
        const int rowb = r0 + hi * 4;
        #pragma unroll
        for (int rr = 0; rr < 4; ++rr)
            C[(size_t)(rowb + rr) * KDIM + c] = acc[ct][rr] + bv;
    }
}

extern "C" void kernel_launch(void* const* d_in, const int* in_sizes, int n_in,
                              void* d_out, int out_size, void* d_ws, size_t ws_size,
                              hipStream_t stream) {
    const float* x    = (const float*)d_in[0];
    const float* pos  = (const float*)d_in[1];
    const float* Wq   = (const float*)d_in[2];
    const float* bq   = (const float*)d_in[3];
    const float* Wk   = (const float*)d_in[4];
    const float* bk   = (const float*)d_in[5];
    const float* Wv   = (const float*)d_in[6];
    const float* bv   = (const float*)d_in[7];
    const float* Wo   = (const float*)d_in[8];
    const float* bo   = (const float*)d_in[9];
    const float* rope = (const float*)d_in[10];
    // d_in[11]=src, d_in[12]=dst: fixed fully-connected pattern, unused.

    char* ws = (char*)d_ws;
    short* WoT  = (short*)(ws);            // 384*384 bf16 = 294,912 B
    short* attn = (short*)(ws + 294912);   // 2048*384 bf16 = 1,572,864 B

    fused_kernel<<<144 + NGRAPHS * GHEADS, 256, 0, stream>>>(
        x, pos, Wq, bq, Wk, bk, Wv, bv, Wo, rope, WoT, attn);

    {
        dim3 grid(NNODES / 16, KDIM / 64);
        out_gemm_kernel<<<grid, 64, 0, stream>>>(attn, WoT, bo, (float*)d_out);
    }
}